// Round 15
// baseline (1192.076 us; speedup 1.0000x reference)
//
#include <hip/hip_runtime.h>
#include <math.h>

#define BB   512
#define TT   256
#define HH   512
#define DIN  514
#define DOUTN 2
#define DT   0.1f
#define TH   (TT * HH)

#define NSL   4      // scan: j-slices per group
#define NGRP  32     // scan: batch groups

typedef short s16x8 __attribute__((ext_vector_type(8)));
typedef float f32x4 __attribute__((ext_vector_type(4)));

__device__ __forceinline__ float retanh_f(float a) {
    float am = fminf(a, 15.0f);
    float E  = __expf(2.0f * am);
    float tp = __fdividef(E - 1.0f, E + 1.0f);
    return a > 0.0f ? tp : 0.0f;
}

__device__ __forceinline__ unsigned short f2bf(float f) {
    unsigned u = __float_as_uint(f);
    unsigned r = (u + 0x7FFFu + ((u >> 16) & 1u)) >> 16;
    return (unsigned short)r;
}

// async global->LDS, 16B per lane; LDS dest = wave-uniform base + lane*16
__device__ __forceinline__ void gload_lds16(const void* g, void* l) {
    __builtin_amdgcn_global_load_lds(
        (const __attribute__((address_space(1))) unsigned int*)g,
        (__attribute__((address_space(3))) unsigned int*)l, 16, 0, 0);
}

// ---------------------------------------------------------------------------
// Kernel 1a: pack W_h into bf16 MFMA B-fragments (PROVEN rounds 6-14).
// ---------------------------------------------------------------------------
__global__ __launch_bounds__(256) void pack_wh(const float* __restrict__ Wh,
                                               unsigned short* __restrict__ Wp) {
    const int idx = blockIdx.x * 256 + threadIdx.x;   // 0..32767
    const int l  = idx & 63;
    const int jt = (idx >> 6) & 31;
    const int kc = idx >> 11;
    const int j  = jt * 16 + (l & 15);
    const int k0 = kc * 32 + (l >> 4) * 8;
    s16x8 pv;
    #pragma unroll
    for (int e = 0; e < 8; ++e) pv[e] = (short)f2bf(Wh[j * HH + k0 + e]);
    *(s16x8*)&Wp[(size_t)idx * 8] = pv;
}

// ---------------------------------------------------------------------------
// Kernel 1b: pack W_x (k<512) into bf16 hi/lo fragments (PROVEN rounds 13-14).
// ---------------------------------------------------------------------------
__global__ __launch_bounds__(256) void pack_wx(const float* __restrict__ Wx,
                                               unsigned short* __restrict__ WfH,
                                               unsigned short* __restrict__ WfL) {
    const int idx = blockIdx.x * 256 + threadIdx.x;   // 0..32767
    const int l  = idx & 63;
    const int jt = (idx >> 6) & 31;
    const int kc = idx >> 11;
    const int j  = jt * 16 + (l & 15);
    const int k0 = kc * 32 + (l >> 4) * 8;
    s16x8 ph, pl;
    #pragma unroll
    for (int e = 0; e < 8; ++e) {
        const float v = Wx[(size_t)j * DIN + k0 + e];
        const unsigned short hi = f2bf(v);
        const float hv = __uint_as_float((unsigned)hi << 16);
        ph[e] = (short)hi;
        pl[e] = (short)f2bf(v - hv);
    }
    *(s16x8*)&WfH[(size_t)idx * 8] = ph;
    *(s16x8*)&WfL[(size_t)idx * 8] = pl;
}

// ---------------------------------------------------------------------------
// Kernel 2 (PROVEN round 14): x2ah via MFMA hi/lo, dbuf global_load_lds W,
// x in registers, LDS-bounced packed epilogue.
// ---------------------------------------------------------------------------
__device__ __forceinline__ void cvt_hilo(float4 a, float4 b, s16x8& hi, s16x8& lo) {
    float v[8] = {a.x, a.y, a.z, a.w, b.x, b.y, b.z, b.w};
    #pragma unroll
    for (int e = 0; e < 8; ++e) {
        const unsigned short h = f2bf(v[e]);
        hi[e] = (short)h;
        lo[e] = (short)f2bf(v[e] - __uint_as_float((unsigned)h << 16));
    }
}

#define STAGE_W(KC, DST) do { \
    const s16x8* gh = WfHv + (size_t)(KC) * 2048 + w * 256 + l; \
    const s16x8* gl = WfLv + (size_t)(KC) * 2048 + w * 256 + l; \
    s16x8* dh = (DST) + w * 256; \
    s16x8* dl = (DST) + 2048 + w * 256; \
    gload_lds16(gh + 0 * 64, dh + 0 * 64); \
    gload_lds16(gh + 1 * 64, dh + 1 * 64); \
    gload_lds16(gh + 2 * 64, dh + 2 * 64); \
    gload_lds16(gh + 3 * 64, dh + 3 * 64); \
    gload_lds16(gl + 0 * 64, dl + 0 * 64); \
    gload_lds16(gl + 1 * 64, dl + 1 * 64); \
    gload_lds16(gl + 2 * 64, dl + 2 * 64); \
    gload_lds16(gl + 3 * 64, dl + 3 * 64); \
} while (0)

__global__ __launch_bounds__(512) void x2ah_mfma(const float* __restrict__ X,
                                                 const unsigned short* __restrict__ WfH,
                                                 const unsigned short* __restrict__ WfL,
                                                 const float* __restrict__ Wx,
                                                 const float* __restrict__ bias,
                                                 const float* __restrict__ noise,
                                                 unsigned int* __restrict__ outp) {
    __shared__ __align__(16) char arena[2][65536];   // [buf][hi 32KB | lo 32KB]

    const int tid = threadIdx.x;
    const int l   = tid & 63;
    const int w   = tid >> 6;
    const int lm  = l & 15;
    const int lg  = l >> 4;
    const int lg4 = lg * 4;
    const int lg8 = lg * 8;
    const int r0  = blockIdx.x * 128;

    const int rt  = w & 3;
    const int jt0 = (w >> 2) * 16;

    const s16x8* WfHv = (const s16x8*)WfH;
    const s16x8* WfLv = (const s16x8*)WfL;

    const float* xr0 = X + (size_t)(r0 + rt * 32 + lm) * DIN;
    const float* xr1 = xr0 + 16 * DIN;

    float4 xa0 = *(const float4*)(xr0 + lg8);
    float4 xb0 = *(const float4*)(xr0 + lg8 + 4);
    float4 xa1 = *(const float4*)(xr1 + lg8);
    float4 xb1 = *(const float4*)(xr1 + lg8 + 4);
    STAGE_W(0, (s16x8*)arena[0]);
    __syncthreads();

    f32x4 acc0[16], acc1[16];
    #pragma unroll
    for (int jt = 0; jt < 16; ++jt) {
        acc0[jt] = (f32x4){0.f, 0.f, 0.f, 0.f};
        acc1[jt] = (f32x4){0.f, 0.f, 0.f, 0.f};
    }

    for (int kc = 0; kc < 16; ++kc) {
        s16x8* cur = (s16x8*)arena[kc & 1];
        s16x8* nxt = (s16x8*)arena[(kc & 1) ^ 1];
        if (kc < 15) STAGE_W(kc + 1, nxt);

        s16x8 Ah0, Al0, Ah1, Al1;
        cvt_hilo(xa0, xb0, Ah0, Al0);
        cvt_hilo(xa1, xb1, Ah1, Al1);
        if (kc < 15) {
            const int off = (kc + 1) * 32 + lg8;
            xa0 = *(const float4*)(xr0 + off);
            xb0 = *(const float4*)(xr0 + off + 4);
            xa1 = *(const float4*)(xr1 + off);
            xb1 = *(const float4*)(xr1 + off + 4);
        }

        #pragma unroll
        for (int jt = 0; jt < 16; ++jt) {
            const s16x8 Bh = cur[(jt0 + jt) * 64 + l];
            const s16x8 Bl = cur[2048 + (jt0 + jt) * 64 + l];
            acc0[jt] = __builtin_amdgcn_mfma_f32_16x16x32_bf16(Ah0, Bh, acc0[jt], 0, 0, 0);
            acc0[jt] = __builtin_amdgcn_mfma_f32_16x16x32_bf16(Al0, Bh, acc0[jt], 0, 0, 0);
            acc0[jt] = __builtin_amdgcn_mfma_f32_16x16x32_bf16(Ah0, Bl, acc0[jt], 0, 0, 0);
            acc1[jt] = __builtin_amdgcn_mfma_f32_16x16x32_bf16(Ah1, Bh, acc1[jt], 0, 0, 0);
            acc1[jt] = __builtin_amdgcn_mfma_f32_16x16x32_bf16(Al1, Bh, acc1[jt], 0, 0, 0);
            acc1[jt] = __builtin_amdgcn_mfma_f32_16x16x32_bf16(Ah1, Bl, acc1[jt], 0, 0, 0);
        }
        __syncthreads();
    }

    unsigned short* ls = (unsigned short*)arena;   // [16][512]
    for (int c = 0; c < 8; ++c) {
        if (rt == (c >> 1)) {
            float xt0[4], xt1[4];
            #pragma unroll
            for (int r = 0; r < 4; ++r) {
                const float* xrow = X + (size_t)(r0 + c * 16 + lg4 + r) * DIN + 512;
                xt0[r] = xrow[0];
                xt1[r] = xrow[1];
            }
            #pragma unroll
            for (int jt = 0; jt < 16; ++jt) {
                const int j = (jt0 + jt) * 16 + lm;
                const float2 wt = *(const float2*)&Wx[(size_t)j * DIN + 512];
                const float bj = bias[j];
                #pragma unroll
                for (int r = 0; r < 4; ++r) {
                    const float av = (c & 1) ? acc1[jt][r] : acc0[jt][r];
                    const float v = av + bj + xt0[r] * wt.x + xt1[r] * wt.y;
                    ls[(lg4 + r) * 512 + j] = f2bf(v);
                }
            }
        }
        __syncthreads();
        {
            const int i   = tid * 16;
            const int row = i >> 9, col = i & 511;
            const size_t gi = (size_t)(r0 + c * 16 + row) * HH + col;
            const float4 n0 = *(const float4*)&noise[gi + 0];
            const float4 n1 = *(const float4*)&noise[gi + 4];
            const float4 n2 = *(const float4*)&noise[gi + 8];
            const float4 n3 = *(const float4*)&noise[gi + 12];
            const unsigned short* lp = &ls[row * 512 + col];
            const uint4 la = *(const uint4*)lp;
            const uint4 lb = *(const uint4*)(lp + 8);
            uint4 o0, o1, o2, o3;
            o0.x = ((la.x & 0xffffu) << 16) | f2bf(n0.x);
            o0.y = (la.x & 0xffff0000u)     | f2bf(n0.y);
            o0.z = ((la.y & 0xffffu) << 16) | f2bf(n0.z);
            o0.w = (la.y & 0xffff0000u)     | f2bf(n0.w);
            o1.x = ((la.z & 0xffffu) << 16) | f2bf(n1.x);
            o1.y = (la.z & 0xffff0000u)     | f2bf(n1.y);
            o1.z = ((la.w & 0xffffu) << 16) | f2bf(n1.z);
            o1.w = (la.w & 0xffff0000u)     | f2bf(n1.w);
            o2.x = ((lb.x & 0xffffu) << 16) | f2bf(n2.x);
            o2.y = (lb.x & 0xffff0000u)     | f2bf(n2.y);
            o2.z = ((lb.y & 0xffffu) << 16) | f2bf(n2.z);
            o2.w = (lb.y & 0xffff0000u)     | f2bf(n2.w);
            o3.x = ((lb.z & 0xffffu) << 16) | f2bf(n3.x);
            o3.y = (lb.z & 0xffff0000u)     | f2bf(n3.y);
            o3.z = ((lb.w & 0xffffu) << 16) | f2bf(n3.z);
            o3.w = (lb.w & 0xffff0000u)     | f2bf(n3.w);
            *(uint4*)&outp[gi + 0]  = o0;
            *(uint4*)&outp[gi + 4]  = o1;
            *(uint4*)&outp[gi + 8]  = o2;
            *(uint4*)&outp[gi + 12] = o3;
        }
        __syncthreads();
    }
}

// ---------------------------------------------------------------------------
// Kernel 3 (round 15): j-sliced MFMA scan, LLC h-exchange, 2-barrier protocol.
//   - direct register publish (4x u16 agent stores) -> no BAR2, no hs writes
//   - vmcnt(0) covers publish ONLY (hio stores moved after the flag)
//   - per-wave flags (8/slice) -> no BAR3; poll = 32 threads x 1 flag
//   - BAR1 subsumed by BAR4 (gather is the only hs writer)
//   - fused output projection (Wy staged in LDS) -> out_kernel removed
// ---------------------------------------------------------------------------
#define WKLOAD(KC) s16x8 wk##KC = WpV[((KC) * 32 + s * 8 + w) * 64 + l]
#define WKPIN(A, B, C, D) asm volatile("" : "+v"(A), "+v"(B), "+v"(C), "+v"(D))

#define KC_EVEN(KC) do { \
    const s16x8 A = *(const s16x8*)&hrow[(KC) * 32]; \
    accA = __builtin_amdgcn_mfma_f32_16x16x32_bf16(A, wk##KC, accA, 0, 0, 0); \
} while (0)
#define KC_ODD(KC) do { \
    const s16x8 A = *(const s16x8*)&hrow[(KC) * 32]; \
    accB = __builtin_amdgcn_mfma_f32_16x16x32_bf16(A, wk##KC, accB, 0, 0, 0); \
} while (0)

__global__ __launch_bounds__(512) void scan15_kernel(const unsigned short* __restrict__ Wp,
                                                     const float* __restrict__ ah0,
                                                     const float* __restrict__ Wy,
                                                     unsigned int* __restrict__ hio,
                                                     float* __restrict__ out0,
                                                     unsigned short* inbox,
                                                     unsigned int* flags) {
    __shared__ __align__(16) unsigned short hs[16][520];
    __shared__ float wy[2][512];

    const int tid = threadIdx.x;
    const int l   = tid & 63;
    const int w   = tid >> 6;
    const int lm  = l & 15;
    const int lg  = l >> 4;
    const int lg4 = lg * 4;
    const int gid = blockIdx.x;
    const int g   = gid >> 2;
    const int s   = gid & 3;
    const int b0  = g * 16;

    const s16x8* WpV = (const s16x8*)Wp;

    WKLOAD(0);  WKLOAD(1);  WKLOAD(2);  WKLOAD(3);
    WKLOAD(4);  WKLOAD(5);  WKLOAD(6);  WKLOAD(7);
    WKLOAD(8);  WKLOAD(9);  WKLOAD(10); WKLOAD(11);
    WKLOAD(12); WKLOAD(13); WKLOAD(14); WKLOAD(15);
    WKPIN(wk0, wk1, wk2, wk3);     WKPIN(wk4, wk5, wk6, wk7);
    WKPIN(wk8, wk9, wk10, wk11);   WKPIN(wk12, wk13, wk14, wk15);

    const int jn = (s * 8 + w) * 16 + lm;

    f32x4 ahv;
    {
        const float a0 = ah0[jn];
        ahv = (f32x4){a0, a0, a0, a0};
    }

    // stage Wy (fp32, 4 KB) and init hs(t=0)
    for (int i = tid; i < 2 * 512; i += 512) wy[i >> 9][i & 511] = Wy[i];
    for (int idx = tid; idx < 16 * 512; idx += 512) {
        int b = idx >> 9, k = idx & 511;
        hs[b][k] = f2bf(retanh_f(ah0[k]));
    }
    __syncthreads();

    const unsigned short* hrow = &hs[lm][lg * 8];

    const int pb = tid >> 5;
    const int pq = tid & 31;
    unsigned long long* ibx = (unsigned long long*)inbox;
    const int gatIdx = ((b0 + pb) << 7) + pq;           // u64 index
    const int pubBase = (b0 + lg4) * 512 + jn;          // u16 index (row 0)

    // fused-out mapping: wave w -> batch 4s+(w>>1), output o = w&1
    const int obid = 4 * s + (w >> 1);
    const int oo   = w & 1;

    int gb = (b0 + lg4) * TH + jn;

    unsigned int pk0 = hio[gb + 0 * TH];
    unsigned int pk1 = hio[gb + 1 * TH];
    unsigned int pk2 = hio[gb + 2 * TH];
    unsigned int pk3 = hio[gb + 3 * TH];

    for (int t = 0; t < TT; ++t) {
        const int par64 = (t & 1) << 16;   // u64 units
        const int par16 = (t & 1) << 18;   // u16 units

        // ---- GEMM: acc = hs(t-1) @ W[:, jtile] ----
        f32x4 accA = (f32x4){0.f, 0.f, 0.f, 0.f};
        f32x4 accB = (f32x4){0.f, 0.f, 0.f, 0.f};
        KC_EVEN(0);  KC_ODD(1);  KC_EVEN(2);  KC_ODD(3);
        KC_EVEN(4);  KC_ODD(5);  KC_EVEN(6);  KC_ODD(7);
        KC_EVEN(8);  KC_ODD(9);  KC_EVEN(10); KC_ODD(11);
        KC_EVEN(12); KC_ODD(13); KC_EVEN(14); KC_ODD(15);
        const f32x4 acc = accA + accB;

        // ---- epilogue in registers (no LDS) ----
        float h0f, h1f, h2f, h3f;
        {
            float a;
            a = ahv[0];
            a += DT * (acc[0] + __uint_as_float(pk0 & 0xffff0000u) - a);
            ahv[0] = a; h0f = retanh_f(a) + __uint_as_float(pk0 << 16);
            a = ahv[1];
            a += DT * (acc[1] + __uint_as_float(pk1 & 0xffff0000u) - a);
            ahv[1] = a; h1f = retanh_f(a) + __uint_as_float(pk1 << 16);
            a = ahv[2];
            a += DT * (acc[2] + __uint_as_float(pk2 & 0xffff0000u) - a);
            ahv[2] = a; h2f = retanh_f(a) + __uint_as_float(pk2 << 16);
            a = ahv[3];
            a += DT * (acc[3] + __uint_as_float(pk3 & 0xffff0000u) - a);
            ahv[3] = a; h3f = retanh_f(a) + __uint_as_float(pk3 << 16);
        }

        // ---- direct publish from registers (bf16), FIRST vmem of this step ----
        {
            unsigned short* pbase = inbox + par16 + pubBase;
            __hip_atomic_store(&pbase[0 * 512], f2bf(h0f), __ATOMIC_RELAXED,
                               __HIP_MEMORY_SCOPE_AGENT);
            __hip_atomic_store(&pbase[1 * 512], f2bf(h1f), __ATOMIC_RELAXED,
                               __HIP_MEMORY_SCOPE_AGENT);
            __hip_atomic_store(&pbase[2 * 512], f2bf(h2f), __ATOMIC_RELAXED,
                               __HIP_MEMORY_SCOPE_AGENT);
            __hip_atomic_store(&pbase[3 * 512], f2bf(h3f), __ATOMIC_RELAXED,
                               __HIP_MEMORY_SCOPE_AGENT);
        }
        asm volatile("s_waitcnt vmcnt(0)" ::: "memory");   // drains publish only

        // ---- per-wave flag (no barrier) ----
        unsigned int* fl = flags + ((size_t)(t * NGRP + g) * NSL + s) * 8;
        if (l == 0)
            __hip_atomic_store(&fl[w], 1u, __ATOMIC_RELAXED, __HIP_MEMORY_SCOPE_AGENT);

        // ---- deferred hio stores + next-step pk prefetch (off critical path) ----
        hio[gb + 0 * TH] = __float_as_uint(h0f);
        hio[gb + 1 * TH] = __float_as_uint(h1f);
        hio[gb + 2 * TH] = __float_as_uint(h2f);
        hio[gb + 3 * TH] = __float_as_uint(h3f);
        if (t + 1 < TT) {
            pk0 = hio[gb + HH + 0 * TH];
            pk1 = hio[gb + HH + 1 * TH];
            pk2 = hio[gb + HH + 2 * TH];
            pk3 = hio[gb + HH + 3 * TH];
        }

        // ---- poll: 32 threads, one (slice,wave) flag each ----
        if (tid < 32) {
            const unsigned int* fp = flags
                + ((size_t)(t * NGRP + g) * NSL + (tid >> 3)) * 8 + (tid & 7);
            while (__hip_atomic_load(fp, __ATOMIC_RELAXED,
                                     __HIP_MEMORY_SCOPE_AGENT) == 0u)
                __builtin_amdgcn_s_sleep(1);
        }
        __syncthreads();   // BAR4: flags seen + all GEMM reads of hs done

        // ---- gather group's full h(t) into hs (lane-consecutive u64s) ----
        {
            const unsigned long long g0 = __hip_atomic_load(&ibx[par64 + gatIdx + 0 * 32],
                __ATOMIC_RELAXED, __HIP_MEMORY_SCOPE_AGENT);
            const unsigned long long g1 = __hip_atomic_load(&ibx[par64 + gatIdx + 1 * 32],
                __ATOMIC_RELAXED, __HIP_MEMORY_SCOPE_AGENT);
            const unsigned long long g2 = __hip_atomic_load(&ibx[par64 + gatIdx + 2 * 32],
                __ATOMIC_RELAXED, __HIP_MEMORY_SCOPE_AGENT);
            const unsigned long long g3 = __hip_atomic_load(&ibx[par64 + gatIdx + 3 * 32],
                __ATOMIC_RELAXED, __HIP_MEMORY_SCOPE_AGENT);
            *(unsigned long long*)&hs[pb][pq * 4 + 0 * 128] = g0;
            *(unsigned long long*)&hs[pb][pq * 4 + 1 * 128] = g1;
            *(unsigned long long*)&hs[pb][pq * 4 + 2 * 128] = g2;
            *(unsigned long long*)&hs[pb][pq * 4 + 3 * 128] = g3;
        }
        __syncthreads();   // BAR5: hs(t) ready

        // ---- fused output projection: out[b0+obid, t, oo] ----
        {
            const s16x8 hv = *(const s16x8*)&hs[obid][l * 8];
            const float4 w0 = *(const float4*)&wy[oo][l * 8];
            const float4 w1 = *(const float4*)&wy[oo][l * 8 + 4];
            float p = __uint_as_float(((unsigned)(unsigned short)hv[0]) << 16) * w0.x
                    + __uint_as_float(((unsigned)(unsigned short)hv[1]) << 16) * w0.y
                    + __uint_as_float(((unsigned)(unsigned short)hv[2]) << 16) * w0.z
                    + __uint_as_float(((unsigned)(unsigned short)hv[3]) << 16) * w0.w
                    + __uint_as_float(((unsigned)(unsigned short)hv[4]) << 16) * w1.x
                    + __uint_as_float(((unsigned)(unsigned short)hv[5]) << 16) * w1.y
                    + __uint_as_float(((unsigned)(unsigned short)hv[6]) << 16) * w1.z
                    + __uint_as_float(((unsigned)(unsigned short)hv[7]) << 16) * w1.w;
            #pragma unroll
            for (int off = 32; off > 0; off >>= 1) p += __shfl_xor(p, off);
            if (l == 0)
                out0[((size_t)(b0 + obid) * TT + t) * 2 + oo] = p;
        }

        gb += HH;
    }
}

// ---------------------------------------------------------------------------
extern "C" void kernel_launch(void* const* d_in, const int* in_sizes, int n_in,
                              void* d_out, int out_size, void* d_ws, size_t ws_size,
                              hipStream_t stream) {
    const float* x     = (const float*)d_in[0];  // [B,T,DIN]
    const float* noise = (const float*)d_in[1];  // [B,T,H]
    const float* Wx    = (const float*)d_in[2];  // [H,DIN]
    const float* bah   = (const float*)d_in[3];  // [H]
    const float* Wh    = (const float*)d_in[4];  // [H,H]
    const float* Wy    = (const float*)d_in[5];  // [DOUT,H]
    const float* ah0   = (const float*)d_in[6];  // [H]

    float* out0   = (float*)d_out;                   // [B,T,DOUT]
    float* hstore = (float*)d_out + BB * TT * DOUTN; // [B,T,H]

    const size_t FRAG_U16 = (size_t)16 * 32 * 64 * 8;      // 512 KB
    unsigned short* Wp    = (unsigned short*)d_ws;
    unsigned short* WxH   = Wp + FRAG_U16;
    unsigned short* WxL   = WxH + FRAG_U16;
    unsigned short* inbox = WxL + FRAG_U16;                 // 1 MB (2 parities)
    unsigned int*   flags = (unsigned int*)(inbox + 2 * BB * HH);  // 1 MB

    pack_wh<<<16 * 32 * 64 / 256, 256, 0, stream>>>(Wh, Wp);
    pack_wx<<<16 * 32 * 64 / 256, 256, 0, stream>>>(Wx, WxH, WxL);
    x2ah_mfma<<<BB * TT / 128, 512, 0, stream>>>(x, WxH, WxL, Wx, bah, noise,
                                                 (unsigned int*)hstore);

    hipMemsetAsync(flags, 0, (size_t)TT * NGRP * NSL * 8 * sizeof(unsigned int),
                   stream);
    {
        const unsigned short* wpp = Wp;
        unsigned int* hiop = (unsigned int*)hstore;
        float* outp = out0;
        unsigned short* ibp = inbox;
        unsigned int* flp = flags;
        void* args[] = { (void*)&wpp, (void*)&ah0, (void*)&Wy, (void*)&hiop,
                         (void*)&outp, (void*)&ibp, (void*)&flp };
        hipLaunchCooperativeKernel((void*)scan15_kernel, dim3(NGRP * NSL),
                                   dim3(512), args, 0, stream);
    }
}